// Round 5
// baseline (627.269 us; speedup 1.0000x reference)
//
#include <hip/hip_runtime.h>
#include <hip/hip_bf16.h>
#include <cstdint>

// MoRALinear: out[m,o] = sum_i x[m,i] * (W[o,i] + A[o&1023, i&1023]) + b[o]
// R5: 256x256 tile, BK=32, 8-wave, 4-slot LDS ring, counted vmcnt(8),
//     mfma_f32_32x32x16_bf16 (16 MFMA / K-tile), ONE phase per K-tile
//     (2 barriers instead of 4), fragment-major ws panels, setprio,
//     XCD-chunked nb-major block order.
//
// Fragment-major layout per (mb|nb, kt) tile: 16 frags x 512 elems,
//   frag f = rb*2 + kh (rb=row-block of 32, kh=k-half of 16):
//   elem(f*512 + l*8 + j) = M[rb*32 + (l&31)][kt*32 + kh*16 + (l>>5)*8 + j]
// -> global_load_lds stages linearly; ds_read_b128 = base + lane*16B.

typedef __attribute__((ext_vector_type(8))) short bf16x8;
typedef __attribute__((ext_vector_type(16))) float f32x16;
typedef __attribute__((ext_vector_type(4))) float fvec4;

static constexpr int MTOT = 16384;   // B*S
static constexpr int KF   = 4096;    // IN_F
static constexpr int NF   = 4096;    // OUT_F
static constexpr int BM = 256, BN = 256, BK = 32;
static constexpr int TILE = BM * BK;          // 8192 bf16 elems per K-tile panel
static constexpr int KT = KF / BK;            // 128 K-tiles
static constexpr int MB = MTOT / BM;          // 64
static constexpr int NB = NF / BN;            // 16

// ---------------- prep: x -> bf16, fragment-major (32x32x16 frags) -----------
__global__ __launch_bounds__(256) void tile_x_kernel(const float* __restrict__ x,
                                                     __hip_bfloat16* __restrict__ xt) {
    int blk = blockIdx.x;               // mb*KT + kt ; grid = 64*128
    int mb = blk >> 7, kt = blk & 127;
    int tid = threadIdx.x;
    __hip_bfloat16* dst = xt + (size_t)blk * TILE;
#pragma unroll
    for (int it = 0; it < 4; ++it) {
        int e = (it * 256 + tid) * 8;   // element within tile, 0..8191
        int f = e >> 9;                 // fragment 0..15
        int l = (e >> 3) & 63;          // lane 0..63
        int rb = f >> 1, kh = f & 1;
        int row = mb * BM + rb * 32 + (l & 31);
        int k0  = kt * BK + kh * 16 + (l >> 5) * 8;
        const fvec4* s = (const fvec4*)(x + (size_t)row * KF + k0);
        fvec4 v0 = s[0], v1 = s[1];
        union { bf16x8 v; __hip_bfloat16 h[8]; } o;
        o.h[0] = __float2bfloat16(v0[0]); o.h[1] = __float2bfloat16(v0[1]);
        o.h[2] = __float2bfloat16(v0[2]); o.h[3] = __float2bfloat16(v0[3]);
        o.h[4] = __float2bfloat16(v1[0]); o.h[5] = __float2bfloat16(v1[1]);
        o.h[6] = __float2bfloat16(v1[2]); o.h[7] = __float2bfloat16(v1[3]);
        *(bf16x8*)(dst + e) = o.v;
    }
}

// ---------------- prep: W' = W + tiled(A) -> bf16 fragment-major -------------
__global__ __launch_bounds__(256) void tile_w_kernel(const float* __restrict__ W,
                                                     const float* __restrict__ A,
                                                     __hip_bfloat16* __restrict__ wt) {
    int blk = blockIdx.x;               // nb*KT + kt ; grid = 16*128
    int nb = blk >> 7, kt = blk & 127;
    int tid = threadIdx.x;
    __hip_bfloat16* dst = wt + (size_t)blk * TILE;
#pragma unroll
    for (int it = 0; it < 4; ++it) {
        int e = (it * 256 + tid) * 8;
        int f = e >> 9;
        int l = (e >> 3) & 63;
        int rb = f >> 1, kh = f & 1;
        int o  = nb * BN + rb * 32 + (l & 31);
        int k0 = kt * BK + kh * 16 + (l >> 5) * 8;
        const fvec4* sw = (const fvec4*)(W + (size_t)o * KF + k0);
        const fvec4* sa = (const fvec4*)(A + (size_t)(o & 1023) * 1024 + (k0 & 1023));
        fvec4 w0 = sw[0], w1 = sw[1];
        fvec4 a0 = sa[0], a1 = sa[1];
        union { bf16x8 v; __hip_bfloat16 h[8]; } ov;
        ov.h[0] = __float2bfloat16(w0[0] + a0[0]); ov.h[1] = __float2bfloat16(w0[1] + a0[1]);
        ov.h[2] = __float2bfloat16(w0[2] + a0[2]); ov.h[3] = __float2bfloat16(w0[3] + a0[3]);
        ov.h[4] = __float2bfloat16(w1[0] + a1[0]); ov.h[5] = __float2bfloat16(w1[1] + a1[1]);
        ov.h[6] = __float2bfloat16(w1[2] + a1[2]); ov.h[7] = __float2bfloat16(w1[3] + a1[3]);
        *(bf16x8*)(dst + e) = ov.v;
    }
}

// ---------------- async global->LDS (width 16) ----------------
__device__ inline void gload_lds16(const __hip_bfloat16* g, __hip_bfloat16* l) {
    __builtin_amdgcn_global_load_lds(
        (const __attribute__((address_space(1))) unsigned int*)g,
        (__attribute__((address_space(3))) unsigned int*)l, 16, 0, 0);
}

// stage one K-tile (A panel + B panel) = 4 x global_load_lds_dwordx4
#define STG(tt, sl) { const __hip_bfloat16* ga = aP + (size_t)(tt) * TILE;       \
    gload_lds16(ga, As + (sl) * TILE + t8);                                      \
    gload_lds16(ga + 4096, As + (sl) * TILE + 4096 + t8);                        \
    const __hip_bfloat16* gb = bP + (size_t)(tt) * TILE;                         \
    gload_lds16(gb, Bs + (sl) * TILE + t8);                                      \
    gload_lds16(gb + 4096, Bs + (sl) * TILE + 4096 + t8); }

// one phase = one K-tile: stage issue, 12 ds_read_b128, barrier, 16 MFMA,
// vmcnt(8), barrier.  af[fm*2+kh] at aOff + (fm*2+kh)*512; bfv[fn*2+kh] at
// bOff + (fn*2+kh)*512.
#define PHASE(SL, STAGE_STMT) {                                                  \
    STAGE_STMT;                                                                  \
    bf16x8 af[8], bfv[4];                                                        \
    {                                                                            \
        const __hip_bfloat16* ab = As + (SL) * TILE + aOff;                      \
        af[0] = *(const bf16x8*)(ab);                                            \
        af[1] = *(const bf16x8*)(ab + 512);                                      \
        af[2] = *(const bf16x8*)(ab + 1024);                                     \
        af[3] = *(const bf16x8*)(ab + 1536);                                     \
        af[4] = *(const bf16x8*)(ab + 2048);                                     \
        af[5] = *(const bf16x8*)(ab + 2560);                                     \
        af[6] = *(const bf16x8*)(ab + 3072);                                     \
        af[7] = *(const bf16x8*)(ab + 3584);                                     \
        const __hip_bfloat16* bb = Bs + (SL) * TILE + bOff;                      \
        bfv[0] = *(const bf16x8*)(bb);                                           \
        bfv[1] = *(const bf16x8*)(bb + 512);                                     \
        bfv[2] = *(const bf16x8*)(bb + 1024);                                    \
        bfv[3] = *(const bf16x8*)(bb + 1536);                                    \
    }                                                                            \
    asm volatile("" ::: "memory");                                               \
    __builtin_amdgcn_s_barrier();                                                \
    asm volatile("" ::: "memory");                                               \
    __builtin_amdgcn_s_setprio(1);                                               \
    _Pragma("unroll") for (int fm = 0; fm < 4; ++fm)                             \
        _Pragma("unroll") for (int fn = 0; fn < 2; ++fn) {                       \
            acc[fm][fn] = __builtin_amdgcn_mfma_f32_32x32x16_bf16(               \
                af[fm * 2 + 0], bfv[fn * 2 + 0], acc[fm][fn], 0, 0, 0);          \
            acc[fm][fn] = __builtin_amdgcn_mfma_f32_32x32x16_bf16(               \
                af[fm * 2 + 1], bfv[fn * 2 + 1], acc[fm][fn], 0, 0, 0);          \
        }                                                                        \
    __builtin_amdgcn_s_setprio(0);                                               \
    asm volatile("s_waitcnt vmcnt(8)" ::: "memory");                             \
    __builtin_amdgcn_s_barrier();                                                \
    asm volatile("" ::: "memory"); }

__global__ __launch_bounds__(512, 2) void gemm_bf16_kernel(
    const __hip_bfloat16* __restrict__ xt, const __hip_bfloat16* __restrict__ wt,
    const float* __restrict__ bias, float* __restrict__ out) {
    extern __shared__ __hip_bfloat16 lds[];
    __hip_bfloat16* As = lds;                 // 4 slots * 8192
    __hip_bfloat16* Bs = lds + 4 * TILE;      // 4 slots * 8192

    // XCD chunking, nb-major inside chunk: each XCD holds 2 B-panels (L2-resident)
    int bid = blockIdx.x;                     // nwg = 1024
    int wg = (bid & 7) * 128 + (bid >> 3);
    int nb = wg >> 6;                         // 16 col-blocks
    int mb = wg & 63;                         // 64 row-blocks

    int tid = threadIdx.x;
    int lane = tid & 63;
    int wv = tid >> 6;                        // 8 waves
    int wm = wv >> 2, wn = wv & 3;            // 2 x 4 wave grid, 128x64 C each
    int t8 = tid * 8;

    // A frag (rb = wm*4+fm, kh): off = wm*4096 + fm*1024 + kh*512 + lane*8
    // B frag (cb = wn*2+fn, kh): off = wn*2048 + fn*1024 + kh*512 + lane*8
    int aOff = wm * 4096 + lane * 8;
    int bOff = wn * 2048 + lane * 8;

    const __hip_bfloat16* aP = xt + (size_t)mb * (KT * TILE) + t8;
    const __hip_bfloat16* bP = wt + (size_t)nb * (KT * TILE) + t8;

    f32x16 acc[4][2];
#pragma unroll
    for (int fm = 0; fm < 4; ++fm)
#pragma unroll
        for (int fn = 0; fn < 2; ++fn)
#pragma unroll
            for (int r = 0; r < 16; ++r) acc[fm][fn][r] = 0.f;

    // prologue: tiles 0,1,2 -> slots 0,1,2 (12 loads); vmcnt(8) drains tile 0
    STG(0, 0); STG(1, 1); STG(2, 2);
    asm volatile("s_waitcnt vmcnt(8)" ::: "memory");
    __builtin_amdgcn_s_barrier();
    asm volatile("" ::: "memory");

    // main loop: phase t computes K-tile t (slot t&3), stages tile t+3.
    // vmcnt(8) per phase drains tile t+1 before its consumption next phase.
    for (int j = 0; j < KT / 4; ++j) {
        int tb = 4 * j;
        int t4 = tb + 4; if (t4 >= KT) t4 = 0;   // tail: clamp source (slot unused)
        int t5 = tb + 5; if (t5 >= KT) t5 = 0;
        int t6 = tb + 6; if (t6 >= KT) t6 = 0;
        PHASE(0, STG(tb + 3, 3));
        PHASE(1, STG(t4, 0));
        PHASE(2, STG(t5, 1));
        PHASE(3, STG(t6, 2));
    }
    // drain all LDS-DMA before kernel end (no in-flight writes at s_endpgm)
    asm volatile("s_waitcnt vmcnt(0)" ::: "memory");

    // epilogue: 32x32 C/D layout: col = lane&31, row = (reg&3)+8*(reg>>2)+4*(lane>>5)
    int row0 = mb * BM + wm * 128;
    int col0 = nb * BN + wn * 64;
    int ln31 = lane & 31;
    int l5 = lane >> 5;
#pragma unroll
    for (int fn = 0; fn < 2; ++fn) {
        int col = col0 + fn * 32 + ln31;
        float bv = bias[col];
#pragma unroll
        for (int fm = 0; fm < 4; ++fm) {
            int rbase = row0 + fm * 32 + 4 * l5;
#pragma unroll
            for (int r = 0; r < 16; ++r) {
                int row = rbase + (r & 3) + 8 * (r >> 2);
                out[(size_t)row * NF + col] = acc[fm][fn][r] + bv;
            }
        }
    }
}

extern "C" void kernel_launch(void* const* d_in, const int* in_sizes, int n_in,
                              void* d_out, int out_size, void* d_ws, size_t ws_size,
                              hipStream_t stream) {
    const float* x = (const float*)d_in[0];
    const float* W = (const float*)d_in[1];
    const float* b = (const float*)d_in[2];
    const float* A = (const float*)d_in[3];
    float* out = (float*)d_out;

    size_t xt_elems = (size_t)MB * KT * TILE;       // 67.1M elems
    size_t wt_elems = (size_t)NB * KT * TILE;       // 16.8M elems
    size_t need = (xt_elems + wt_elems) * sizeof(__hip_bfloat16);
    if (ws_size < need) return;

    __hip_bfloat16* xt = (__hip_bfloat16*)d_ws;
    __hip_bfloat16* wt = xt + xt_elems;

    (void)hipFuncSetAttribute((const void*)gemm_bf16_kernel,
                              hipFuncAttributeMaxDynamicSharedMemorySize, 131072);

    tile_x_kernel<<<MB * KT, 256, 0, stream>>>(x, xt);
    tile_w_kernel<<<NB * KT, 256, 0, stream>>>(W, A, wt);
    gemm_bf16_kernel<<<MB * NB, 512, 131072, stream>>>(xt, wt, b, out);
}

// Round 6
// 617.021 us; speedup vs baseline: 1.0166x; 1.0166x over previous
//
#include <hip/hip_runtime.h>
#include <hip/hip_bf16.h>
#include <cstdint>

// MoRALinear: out[m,o] = sum_i x[m,i] * (W[o,i] + A[o&1023, i&1023]) + b[o]
// R6: R5 structure (256x256, BK=32, 8-wave, 4-slot ring, vmcnt(8),
//     mfma_32x32x16, fragment-major panels) with ONE barrier per K-tile:
//     the mid-phase barrier between ds_reads and MFMA is removed (redundant
//     by the ring's vmcnt accounting), letting LDS-read and MFMA pipes
//     overlap via intra-phase wave skew on each SIMD.

typedef __attribute__((ext_vector_type(8))) short bf16x8;
typedef __attribute__((ext_vector_type(16))) float f32x16;
typedef __attribute__((ext_vector_type(4))) float fvec4;

static constexpr int MTOT = 16384;   // B*S
static constexpr int KF   = 4096;    // IN_F
static constexpr int NF   = 4096;    // OUT_F
static constexpr int BM = 256, BN = 256, BK = 32;
static constexpr int TILE = BM * BK;          // 8192 bf16 elems per K-tile panel
static constexpr int KT = KF / BK;            // 128 K-tiles
static constexpr int MB = MTOT / BM;          // 64
static constexpr int NB = NF / BN;            // 16

// ---------------- prep: x -> bf16, fragment-major (32x32x16 frags) -----------
__global__ __launch_bounds__(256) void tile_x_kernel(const float* __restrict__ x,
                                                     __hip_bfloat16* __restrict__ xt) {
    int blk = blockIdx.x;               // mb*KT + kt ; grid = 64*128
    int mb = blk >> 7, kt = blk & 127;
    int tid = threadIdx.x;
    __hip_bfloat16* dst = xt + (size_t)blk * TILE;
#pragma unroll
    for (int it = 0; it < 4; ++it) {
        int e = (it * 256 + tid) * 8;   // element within tile, 0..8191
        int f = e >> 9;                 // fragment 0..15
        int l = (e >> 3) & 63;          // lane 0..63
        int rb = f >> 1, kh = f & 1;
        int row = mb * BM + rb * 32 + (l & 31);
        int k0  = kt * BK + kh * 16 + (l >> 5) * 8;
        const fvec4* s = (const fvec4*)(x + (size_t)row * KF + k0);
        fvec4 v0 = s[0], v1 = s[1];
        union { bf16x8 v; __hip_bfloat16 h[8]; } o;
        o.h[0] = __float2bfloat16(v0[0]); o.h[1] = __float2bfloat16(v0[1]);
        o.h[2] = __float2bfloat16(v0[2]); o.h[3] = __float2bfloat16(v0[3]);
        o.h[4] = __float2bfloat16(v1[0]); o.h[5] = __float2bfloat16(v1[1]);
        o.h[6] = __float2bfloat16(v1[2]); o.h[7] = __float2bfloat16(v1[3]);
        *(bf16x8*)(dst + e) = o.v;
    }
}

// ---------------- prep: W' = W + tiled(A) -> bf16 fragment-major -------------
__global__ __launch_bounds__(256) void tile_w_kernel(const float* __restrict__ W,
                                                     const float* __restrict__ A,
                                                     __hip_bfloat16* __restrict__ wt) {
    int blk = blockIdx.x;               // nb*KT + kt ; grid = 16*128
    int nb = blk >> 7, kt = blk & 127;
    int tid = threadIdx.x;
    __hip_bfloat16* dst = wt + (size_t)blk * TILE;
#pragma unroll
    for (int it = 0; it < 4; ++it) {
        int e = (it * 256 + tid) * 8;
        int f = e >> 9;
        int l = (e >> 3) & 63;
        int rb = f >> 1, kh = f & 1;
        int o  = nb * BN + rb * 32 + (l & 31);
        int k0 = kt * BK + kh * 16 + (l >> 5) * 8;
        const fvec4* sw = (const fvec4*)(W + (size_t)o * KF + k0);
        const fvec4* sa = (const fvec4*)(A + (size_t)(o & 1023) * 1024 + (k0 & 1023));
        fvec4 w0 = sw[0], w1 = sw[1];
        fvec4 a0 = sa[0], a1 = sa[1];
        union { bf16x8 v; __hip_bfloat16 h[8]; } ov;
        ov.h[0] = __float2bfloat16(w0[0] + a0[0]); ov.h[1] = __float2bfloat16(w0[1] + a0[1]);
        ov.h[2] = __float2bfloat16(w0[2] + a0[2]); ov.h[3] = __float2bfloat16(w0[3] + a0[3]);
        ov.h[4] = __float2bfloat16(w1[0] + a1[0]); ov.h[5] = __float2bfloat16(w1[1] + a1[1]);
        ov.h[6] = __float2bfloat16(w1[2] + a1[2]); ov.h[7] = __float2bfloat16(w1[3] + a1[3]);
        *(bf16x8*)(dst + e) = ov.v;
    }
}

// ---------------- async global->LDS (width 16) ----------------
__device__ inline void gload_lds16(const __hip_bfloat16* g, __hip_bfloat16* l) {
    __builtin_amdgcn_global_load_lds(
        (const __attribute__((address_space(1))) unsigned int*)g,
        (__attribute__((address_space(3))) unsigned int*)l, 16, 0, 0);
}

// stage one K-tile (A panel + B panel) = 4 x global_load_lds_dwordx4
#define STG(tt, sl) { const __hip_bfloat16* ga = aP + (size_t)(tt) * TILE;       \
    gload_lds16(ga, As + (sl) * TILE + t8);                                      \
    gload_lds16(ga + 4096, As + (sl) * TILE + 4096 + t8);                        \
    const __hip_bfloat16* gb = bP + (size_t)(tt) * TILE;                         \
    gload_lds16(gb, Bs + (sl) * TILE + t8);                                      \
    gload_lds16(gb + 4096, Bs + (sl) * TILE + 4096 + t8); }

// one phase = one K-tile, ONE barrier:
//   STG(t+3); 12 ds_read_b128; MFMA x16 (fine-grained lgkmcnt, no barrier
//   between reads and MFMA); vmcnt(8); s_barrier.
// RAW: slot t's DMA drained by vmcnt(8)+barrier at end of phase t-1.
// WAR: phase t-1 reads of slot (t-1)&3 complete before its MFMAs (lgkmcnt),
//      hence before the end-of-(t-1) barrier; STG(t+3)->slot (t-1)&3 is
//      issued after that barrier. Safe with a single barrier.
#define PHASE(SL, STAGE_STMT) {                                                  \
    STAGE_STMT;                                                                  \
    bf16x8 af[8], bfv[4];                                                        \
    {                                                                            \
        const __hip_bfloat16* ab = As + (SL) * TILE + aOff;                      \
        af[0] = *(const bf16x8*)(ab);                                            \
        af[1] = *(const bf16x8*)(ab + 512);                                      \
        af[2] = *(const bf16x8*)(ab + 1024);                                     \
        af[3] = *(const bf16x8*)(ab + 1536);                                     \
        af[4] = *(const bf16x8*)(ab + 2048);                                     \
        af[5] = *(const bf16x8*)(ab + 2560);                                     \
        af[6] = *(const bf16x8*)(ab + 3072);                                     \
        af[7] = *(const bf16x8*)(ab + 3584);                                     \
        const __hip_bfloat16* bb = Bs + (SL) * TILE + bOff;                      \
        bfv[0] = *(const bf16x8*)(bb);                                           \
        bfv[1] = *(const bf16x8*)(bb + 512);                                     \
        bfv[2] = *(const bf16x8*)(bb + 1024);                                    \
        bfv[3] = *(const bf16x8*)(bb + 1536);                                    \
    }                                                                            \
    __builtin_amdgcn_s_setprio(1);                                               \
    _Pragma("unroll") for (int fm = 0; fm < 4; ++fm)                             \
        _Pragma("unroll") for (int fn = 0; fn < 2; ++fn) {                       \
            acc[fm][fn] = __builtin_amdgcn_mfma_f32_32x32x16_bf16(               \
                af[fm * 2 + 0], bfv[fn * 2 + 0], acc[fm][fn], 0, 0, 0);          \
            acc[fm][fn] = __builtin_amdgcn_mfma_f32_32x32x16_bf16(               \
                af[fm * 2 + 1], bfv[fn * 2 + 1], acc[fm][fn], 0, 0, 0);          \
        }                                                                        \
    __builtin_amdgcn_s_setprio(0);                                               \
    asm volatile("s_waitcnt vmcnt(8)" ::: "memory");                             \
    __builtin_amdgcn_s_barrier();                                                \
    asm volatile("" ::: "memory"); }

__global__ __launch_bounds__(512, 2) void gemm_bf16_kernel(
    const __hip_bfloat16* __restrict__ xt, const __hip_bfloat16* __restrict__ wt,
    const float* __restrict__ bias, float* __restrict__ out) {
    extern __shared__ __hip_bfloat16 lds[];
    __hip_bfloat16* As = lds;                 // 4 slots * 8192
    __hip_bfloat16* Bs = lds + 4 * TILE;      // 4 slots * 8192

    // XCD chunking, nb-major inside chunk: each XCD holds 2 B-panels (L2-resident)
    int bid = blockIdx.x;                     // nwg = 1024
    int wg = (bid & 7) * 128 + (bid >> 3);
    int nb = wg >> 6;                         // 16 col-blocks
    int mb = wg & 63;                         // 64 row-blocks

    int tid = threadIdx.x;
    int lane = tid & 63;
    int wv = tid >> 6;                        // 8 waves
    int wm = wv >> 2, wn = wv & 3;            // 2 x 4 wave grid, 128x64 C each
    int t8 = tid * 8;

    // A frag (rb = wm*4+fm, kh): off = wm*4096 + fm*1024 + kh*512 + lane*8
    // B frag (cb = wn*2+fn, kh): off = wn*2048 + fn*1024 + kh*512 + lane*8
    int aOff = wm * 4096 + lane * 8;
    int bOff = wn * 2048 + lane * 8;

    const __hip_bfloat16* aP = xt + (size_t)mb * (KT * TILE) + t8;
    const __hip_bfloat16* bP = wt + (size_t)nb * (KT * TILE) + t8;

    f32x16 acc[4][2];
#pragma unroll
    for (int fm = 0; fm < 4; ++fm)
#pragma unroll
        for (int fn = 0; fn < 2; ++fn)
#pragma unroll
            for (int r = 0; r < 16; ++r) acc[fm][fn][r] = 0.f;

    // prologue: tiles 0,1,2 -> slots 0,1,2 (12 loads); vmcnt(8) drains tile 0
    STG(0, 0); STG(1, 1); STG(2, 2);
    asm volatile("s_waitcnt vmcnt(8)" ::: "memory");
    __builtin_amdgcn_s_barrier();
    asm volatile("" ::: "memory");

    // main loop: phase t computes K-tile t (slot t&3), stages tile t+3.
    // vmcnt(8) per phase drains tile t+1 before its consumption next phase.
    for (int j = 0; j < KT / 4; ++j) {
        int tb = 4 * j;
        int t4 = tb + 4; if (t4 >= KT) t4 = 0;   // tail: clamp source (slot unused)
        int t5 = tb + 5; if (t5 >= KT) t5 = 0;
        int t6 = tb + 6; if (t6 >= KT) t6 = 0;
        PHASE(0, STG(tb + 3, 3));
        PHASE(1, STG(t4, 0));
        PHASE(2, STG(t5, 1));
        PHASE(3, STG(t6, 2));
    }
    // drain all LDS-DMA before kernel end (no in-flight writes at s_endpgm)
    asm volatile("s_waitcnt vmcnt(0)" ::: "memory");

    // epilogue: 32x32 C/D layout: col = lane&31, row = (reg&3)+8*(reg>>2)+4*(lane>>5)
    int row0 = mb * BM + wm * 128;
    int col0 = nb * BN + wn * 64;
    int ln31 = lane & 31;
    int l5 = lane >> 5;
#pragma unroll
    for (int fn = 0; fn < 2; ++fn) {
        int col = col0 + fn * 32 + ln31;
        float bv = bias[col];
#pragma unroll
        for (int fm = 0; fm < 4; ++fm) {
            int rbase = row0 + fm * 32 + 4 * l5;
#pragma unroll
            for (int r = 0; r < 16; ++r) {
                int row = rbase + (r & 3) + 8 * (r >> 2);
                out[(size_t)row * NF + col] = acc[fm][fn][r] + bv;
            }
        }
    }
}

extern "C" void kernel_launch(void* const* d_in, const int* in_sizes, int n_in,
                              void* d_out, int out_size, void* d_ws, size_t ws_size,
                              hipStream_t stream) {
    const float* x = (const float*)d_in[0];
    const float* W = (const float*)d_in[1];
    const float* b = (const float*)d_in[2];
    const float* A = (const float*)d_in[3];
    float* out = (float*)d_out;

    size_t xt_elems = (size_t)MB * KT * TILE;       // 67.1M elems
    size_t wt_elems = (size_t)NB * KT * TILE;       // 16.8M elems
    size_t need = (xt_elems + wt_elems) * sizeof(__hip_bfloat16);
    if (ws_size < need) return;

    __hip_bfloat16* xt = (__hip_bfloat16*)d_ws;
    __hip_bfloat16* wt = xt + xt_elems;

    (void)hipFuncSetAttribute((const void*)gemm_bf16_kernel,
                              hipFuncAttributeMaxDynamicSharedMemorySize, 131072);

    tile_x_kernel<<<MB * KT, 256, 0, stream>>>(x, xt);
    tile_w_kernel<<<NB * KT, 256, 0, stream>>>(W, A, wt);
    gemm_bf16_kernel<<<MB * NB, 512, 131072, stream>>>(xt, wt, b, out);
}

// Round 7
// 615.184 us; speedup vs baseline: 1.0196x; 1.0030x over previous
//
#include <hip/hip_runtime.h>
#include <hip/hip_bf16.h>
#include <cstdint>

// MoRALinear: out[m,o] = sum_i x[m,i] * (W[o,i] + A[o&1023, i&1023]) + b[o]
// R7: R6 structure (256x256, BK=32, 8-wave, 4-slot ring, mfma_32x32x16,
//     fragment-major panels, 1 barrier/K-tile) + REGISTER DOUBLE-BUFFERING
//     of fragments at kh (K=16) granularity: each sub-phase MFMAs the
//     PREVIOUS sub-phase's fragments while issuing the next sub-phase's
//     ds_reads -> LDS port and matrix pipe run concurrently within a wave.

typedef __attribute__((ext_vector_type(8))) short bf16x8;
typedef __attribute__((ext_vector_type(16))) float f32x16;
typedef __attribute__((ext_vector_type(4))) float fvec4;

static constexpr int MTOT = 16384;   // B*S
static constexpr int KF   = 4096;    // IN_F
static constexpr int NF   = 4096;    // OUT_F
static constexpr int BM = 256, BN = 256, BK = 32;
static constexpr int TILE = BM * BK;          // 8192 bf16 elems per K-tile panel
static constexpr int KT = KF / BK;            // 128 K-tiles
static constexpr int MB = MTOT / BM;          // 64
static constexpr int NB = NF / BN;            // 16

// ---------------- prep: x -> bf16, fragment-major (32x32x16 frags) -----------
__global__ __launch_bounds__(256) void tile_x_kernel(const float* __restrict__ x,
                                                     __hip_bfloat16* __restrict__ xt) {
    int blk = blockIdx.x;               // mb*KT + kt ; grid = 64*128
    int mb = blk >> 7, kt = blk & 127;
    int tid = threadIdx.x;
    __hip_bfloat16* dst = xt + (size_t)blk * TILE;
#pragma unroll
    for (int it = 0; it < 4; ++it) {
        int e = (it * 256 + tid) * 8;   // element within tile, 0..8191
        int f = e >> 9;                 // fragment 0..15
        int l = (e >> 3) & 63;          // lane 0..63
        int rb = f >> 1, kh = f & 1;
        int row = mb * BM + rb * 32 + (l & 31);
        int k0  = kt * BK + kh * 16 + (l >> 5) * 8;
        const fvec4* s = (const fvec4*)(x + (size_t)row * KF + k0);
        fvec4 v0 = s[0], v1 = s[1];
        union { bf16x8 v; __hip_bfloat16 h[8]; } o;
        o.h[0] = __float2bfloat16(v0[0]); o.h[1] = __float2bfloat16(v0[1]);
        o.h[2] = __float2bfloat16(v0[2]); o.h[3] = __float2bfloat16(v0[3]);
        o.h[4] = __float2bfloat16(v1[0]); o.h[5] = __float2bfloat16(v1[1]);
        o.h[6] = __float2bfloat16(v1[2]); o.h[7] = __float2bfloat16(v1[3]);
        *(bf16x8*)(dst + e) = o.v;
    }
}

// ---------------- prep: W' = W + tiled(A) -> bf16 fragment-major -------------
__global__ __launch_bounds__(256) void tile_w_kernel(const float* __restrict__ W,
                                                     const float* __restrict__ A,
                                                     __hip_bfloat16* __restrict__ wt) {
    int blk = blockIdx.x;               // nb*KT + kt ; grid = 16*128
    int nb = blk >> 7, kt = blk & 127;
    int tid = threadIdx.x;
    __hip_bfloat16* dst = wt + (size_t)blk * TILE;
#pragma unroll
    for (int it = 0; it < 4; ++it) {
        int e = (it * 256 + tid) * 8;
        int f = e >> 9;
        int l = (e >> 3) & 63;
        int rb = f >> 1, kh = f & 1;
        int o  = nb * BN + rb * 32 + (l & 31);
        int k0 = kt * BK + kh * 16 + (l >> 5) * 8;
        const fvec4* sw = (const fvec4*)(W + (size_t)o * KF + k0);
        const fvec4* sa = (const fvec4*)(A + (size_t)(o & 1023) * 1024 + (k0 & 1023));
        fvec4 w0 = sw[0], w1 = sw[1];
        fvec4 a0 = sa[0], a1 = sa[1];
        union { bf16x8 v; __hip_bfloat16 h[8]; } ov;
        ov.h[0] = __float2bfloat16(w0[0] + a0[0]); ov.h[1] = __float2bfloat16(w0[1] + a0[1]);
        ov.h[2] = __float2bfloat16(w0[2] + a0[2]); ov.h[3] = __float2bfloat16(w0[3] + a0[3]);
        ov.h[4] = __float2bfloat16(w1[0] + a1[0]); ov.h[5] = __float2bfloat16(w1[1] + a1[1]);
        ov.h[6] = __float2bfloat16(w1[2] + a1[2]); ov.h[7] = __float2bfloat16(w1[3] + a1[3]);
        *(bf16x8*)(dst + e) = ov.v;
    }
}

// ---------------- async global->LDS (width 16) ----------------
__device__ inline void gload_lds16(const __hip_bfloat16* g, __hip_bfloat16* l) {
    __builtin_amdgcn_global_load_lds(
        (const __attribute__((address_space(1))) unsigned int*)g,
        (__attribute__((address_space(3))) unsigned int*)l, 16, 0, 0);
}

// stage one K-tile (A panel + B panel) = 4 x global_load_lds_dwordx4
#define STG(tt, sl) { const __hip_bfloat16* ga = aP + (size_t)(tt) * TILE;       \
    gload_lds16(ga, As + (sl) * TILE + t8);                                      \
    gload_lds16(ga + 4096, As + (sl) * TILE + 4096 + t8);                        \
    const __hip_bfloat16* gb = bP + (size_t)(tt) * TILE;                         \
    gload_lds16(gb, Bs + (sl) * TILE + t8);                                      \
    gload_lds16(gb + 4096, Bs + (sl) * TILE + 4096 + t8); }

// read one kh-set (6 ds_read_b128) into named register set P (Pa0..Pa3,Pb0,Pb1)
#define RD_KH(P, SL, KH) {                                                       \
    const __hip_bfloat16* ab_ = As + (SL) * TILE + aOff + (KH) * 512;            \
    P##a0 = *(const bf16x8*)(ab_);                                               \
    P##a1 = *(const bf16x8*)(ab_ + 1024);                                        \
    P##a2 = *(const bf16x8*)(ab_ + 2048);                                        \
    P##a3 = *(const bf16x8*)(ab_ + 3072);                                        \
    const __hip_bfloat16* bb_ = Bs + (SL) * TILE + bOff + (KH) * 512;            \
    P##b0 = *(const bf16x8*)(bb_);                                               \
    P##b1 = *(const bf16x8*)(bb_ + 1024); }

// 8 MFMAs consuming register set P (one kh-slice of all 4x2 accumulators)
#define MM_KH(P) {                                                               \
    __builtin_amdgcn_s_setprio(1);                                               \
    acc[0][0] = __builtin_amdgcn_mfma_f32_32x32x16_bf16(P##a0, P##b0, acc[0][0], 0, 0, 0); \
    acc[0][1] = __builtin_amdgcn_mfma_f32_32x32x16_bf16(P##a0, P##b1, acc[0][1], 0, 0, 0); \
    acc[1][0] = __builtin_amdgcn_mfma_f32_32x32x16_bf16(P##a1, P##b0, acc[1][0], 0, 0, 0); \
    acc[1][1] = __builtin_amdgcn_mfma_f32_32x32x16_bf16(P##a1, P##b1, acc[1][1], 0, 0, 0); \
    acc[2][0] = __builtin_amdgcn_mfma_f32_32x32x16_bf16(P##a2, P##b0, acc[2][0], 0, 0, 0); \
    acc[2][1] = __builtin_amdgcn_mfma_f32_32x32x16_bf16(P##a2, P##b1, acc[2][1], 0, 0, 0); \
    acc[3][0] = __builtin_amdgcn_mfma_f32_32x32x16_bf16(P##a3, P##b0, acc[3][0], 0, 0, 0); \
    acc[3][1] = __builtin_amdgcn_mfma_f32_32x32x16_bf16(P##a3, P##b1, acc[3][1], 0, 0, 0); \
    __builtin_amdgcn_s_setprio(0); }

// one K-tile step. Invariant: set A enters holding (t,kh0), exits holding
// (t+1,kh0); set B is the kh1 scratch. Reads in each sub-phase are
// independent of that sub-phase's MFMAs (consumed next sub-phase).
#define TILE_STEP(SLT, SLN, STAGE_STMT) {                                        \
    STAGE_STMT;                                                                  \
    RD_KH(B, SLT, 1)     /* read (t,kh1)  */                                     \
    MM_KH(A)             /* mfma (t,kh0)  */                                     \
    RD_KH(A, SLN, 0)     /* read (t+1,kh0)*/                                     \
    MM_KH(B)             /* mfma (t,kh1)  */                                     \
    asm volatile("s_waitcnt vmcnt(4)" ::: "memory");                             \
    __builtin_amdgcn_s_barrier();                                                \
    asm volatile("" ::: "memory"); }

__global__ __launch_bounds__(512, 2) void gemm_bf16_kernel(
    const __hip_bfloat16* __restrict__ xt, const __hip_bfloat16* __restrict__ wt,
    const float* __restrict__ bias, float* __restrict__ out) {
    extern __shared__ __hip_bfloat16 lds[];
    __hip_bfloat16* As = lds;                 // 4 slots * 8192
    __hip_bfloat16* Bs = lds + 4 * TILE;      // 4 slots * 8192

    // XCD chunking, nb-major inside chunk: each XCD holds 2 B-panels (L2-resident)
    int bid = blockIdx.x;                     // nwg = 1024
    int wg = (bid & 7) * 128 + (bid >> 3);
    int nb = wg >> 6;                         // 16 col-blocks
    int mb = wg & 63;                         // 64 row-blocks

    int tid = threadIdx.x;
    int lane = tid & 63;
    int wv = tid >> 6;                        // 8 waves
    int wm = wv >> 2, wn = wv & 3;            // 2 x 4 wave grid, 128x64 C each
    int t8 = tid * 8;

    // A frag (fm, kh): off = wm*4096 + fm*1024 + kh*512 + lane*8
    // B frag (fn, kh): off = wn*2048 + fn*1024 + kh*512 + lane*8
    int aOff = wm * 4096 + lane * 8;
    int bOff = wn * 2048 + lane * 8;

    const __hip_bfloat16* aP = xt + (size_t)mb * (KT * TILE) + t8;
    const __hip_bfloat16* bP = wt + (size_t)nb * (KT * TILE) + t8;

    f32x16 acc[4][2];
#pragma unroll
    for (int fm = 0; fm < 4; ++fm)
#pragma unroll
        for (int fn = 0; fn < 2; ++fn)
#pragma unroll
            for (int r = 0; r < 16; ++r) acc[fm][fn][r] = 0.f;

    bf16x8 Aa0, Aa1, Aa2, Aa3, Ab0, Ab1;      // kh-set A (static names, no
    bf16x8 Ba0, Ba1, Ba2, Ba3, Bb0, Bb1;      // runtime indexing - rule #20)

    // prologue: tiles 0,1,2 -> slots 0,1,2; vmcnt(4) drains tiles 0 AND 1
    STG(0, 0); STG(1, 1); STG(2, 2);
    asm volatile("s_waitcnt vmcnt(4)" ::: "memory");
    __builtin_amdgcn_s_barrier();
    asm volatile("" ::: "memory");
    RD_KH(A, 0, 0)                            // prime set A with (t=0, kh0)

    // main loop: step t computes K-tile t (slot t&3), stages tile t+3,
    // pre-reads (t+1,kh0). End-of-step vmcnt(4) drains tile t+2, so tile
    // t+2 is resident when step t+1 pre-reads it.
    for (int j = 0; j < KT / 4; ++j) {
        int tb = 4 * j;
        int t4 = tb + 4; if (t4 >= KT) t4 = 0;   // tail: clamp source (data unused)
        int t5 = tb + 5; if (t5 >= KT) t5 = 0;
        int t6 = tb + 6; if (t6 >= KT) t6 = 0;
        TILE_STEP(0, 1, STG(tb + 3, 3));
        TILE_STEP(1, 2, STG(t4, 0));
        TILE_STEP(2, 3, STG(t5, 1));
        TILE_STEP(3, 0, STG(t6, 2));
    }
    // drain all LDS-DMA before kernel end (no in-flight writes at s_endpgm)
    asm volatile("s_waitcnt vmcnt(0)" ::: "memory");

    // epilogue: 32x32 C/D layout: col = lane&31, row = (reg&3)+8*(reg>>2)+4*(lane>>5)
    int row0 = mb * BM + wm * 128;
    int col0 = nb * BN + wn * 64;
    int ln31 = lane & 31;
    int l5 = lane >> 5;
#pragma unroll
    for (int fn = 0; fn < 2; ++fn) {
        int col = col0 + fn * 32 + ln31;
        float bv = bias[col];
#pragma unroll
        for (int fm = 0; fm < 4; ++fm) {
            int rbase = row0 + fm * 32 + 4 * l5;
#pragma unroll
            for (int r = 0; r < 16; ++r) {
                int row = rbase + (r & 3) + 8 * (r >> 2);
                out[(size_t)row * NF + col] = acc[fm][fn][r] + bv;
            }
        }
    }
}

extern "C" void kernel_launch(void* const* d_in, const int* in_sizes, int n_in,
                              void* d_out, int out_size, void* d_ws, size_t ws_size,
                              hipStream_t stream) {
    const float* x = (const float*)d_in[0];
    const float* W = (const float*)d_in[1];
    const float* b = (const float*)d_in[2];
    const float* A = (const float*)d_in[3];
    float* out = (float*)d_out;

    size_t xt_elems = (size_t)MB * KT * TILE;       // 67.1M elems
    size_t wt_elems = (size_t)NB * KT * TILE;       // 16.8M elems
    size_t need = (xt_elems + wt_elems) * sizeof(__hip_bfloat16);
    if (ws_size < need) return;

    __hip_bfloat16* xt = (__hip_bfloat16*)d_ws;
    __hip_bfloat16* wt = xt + xt_elems;

    (void)hipFuncSetAttribute((const void*)gemm_bf16_kernel,
                              hipFuncAttributeMaxDynamicSharedMemorySize, 131072);

    tile_x_kernel<<<MB * KT, 256, 0, stream>>>(x, xt);
    tile_w_kernel<<<NB * KT, 256, 0, stream>>>(W, A, wt);
    gemm_bf16_kernel<<<MB * NB, 512, 131072, stream>>>(xt, wt, b, out);
}

// Round 8
// 587.406 us; speedup vs baseline: 1.0679x; 1.0473x over previous
//
#include <hip/hip_runtime.h>
#include <hip/hip_bf16.h>
#include <cstdint>

// MoRALinear: out[m,o] = sum_i x[m,i] * (W[o,i] + A[o&1023, i&1023]) + b[o]
// R8: faithful m201 8-phase port. 256x256 tile, BK=64, 8 waves (2Mx4N),
//     per-wave C 128x64. LDS 128 KiB = 2buf x 2half x (128x64) x {A,B}.
//     Per K64-tile: 4 quadrant-phases, each = {ds_read subtile, stage 1
//     half-tile, barrier+sched_barrier(0), setprio(1), 16 MFMA, setprio(0),
//     [vmcnt(4) at p4], barrier}. Fragment-major panels keep every
//     ds_read_b128 at base+lane*16B (conflict-free) and staging linear.

typedef __attribute__((ext_vector_type(8))) short bf16x8;
typedef __attribute__((ext_vector_type(4))) float f32x4;
typedef __attribute__((ext_vector_type(4))) float fvec4;

static constexpr int MTOT = 16384;   // B*S
static constexpr int KF   = 4096;    // IN_F
static constexpr int NF   = 4096;    // OUT_F
static constexpr int BM = 256, BN = 256, BK = 64;
static constexpr int KT = KF / BK;            // 64 K-tiles of 64
static constexpr int HALF = 128 * 64;         // 8192 elems per half-tile
static constexpr int MB = MTOT / BM;          // 64
static constexpr int NB = NF / BN;            // 16

// Fragment-major half-tile layout (16x16x32 frags), g = fragrow*2 + kk:
//   elem(g*512 + l*8 + j) = M[(g>>1)*16 + (l&15)][(g&1)*32 + (l>>4)*8 + j]
// (M = 128-row x 64-k half of the 256-row tile)

// ---------------- prep: x -> bf16 half-tile panels [mb][kt][h][g][l][8] ------
__global__ __launch_bounds__(256) void tile_x_kernel(const float* __restrict__ x,
                                                     __hip_bfloat16* __restrict__ xt) {
    int blk = blockIdx.x;               // grid = 64*64*2 = 8192
    int mb = blk >> 7;
    int r  = blk & 127;
    int kt = r >> 1, h = r & 1;
    int tid = threadIdx.x;
    __hip_bfloat16* dst = xt + (size_t)blk * HALF;
#pragma unroll
    for (int it = 0; it < 4; ++it) {
        int e = (it * 256 + tid) * 8;   // 0..8191
        int g = e >> 9;                 // frag 0..15
        int l = (e >> 3) & 63;          // lane 0..63
        int row = mb * BM + h * 128 + (g >> 1) * 16 + (l & 15);
        int k0  = kt * BK + (g & 1) * 32 + (l >> 4) * 8;
        const fvec4* s = (const fvec4*)(x + (size_t)row * KF + k0);
        fvec4 v0 = s[0], v1 = s[1];
        union { bf16x8 v; __hip_bfloat16 hh[8]; } o;
        o.hh[0] = __float2bfloat16(v0[0]); o.hh[1] = __float2bfloat16(v0[1]);
        o.hh[2] = __float2bfloat16(v0[2]); o.hh[3] = __float2bfloat16(v0[3]);
        o.hh[4] = __float2bfloat16(v1[0]); o.hh[5] = __float2bfloat16(v1[1]);
        o.hh[6] = __float2bfloat16(v1[2]); o.hh[7] = __float2bfloat16(v1[3]);
        *(bf16x8*)(dst + e) = o.v;
    }
}

// ---------------- prep: W' = W + tiled(A) -> bf16 half-tile panels -----------
__global__ __launch_bounds__(256) void tile_w_kernel(const float* __restrict__ W,
                                                     const float* __restrict__ A,
                                                     __hip_bfloat16* __restrict__ wt) {
    int blk = blockIdx.x;               // grid = 16*64*2 = 2048
    int nb = blk >> 7;
    int r  = blk & 127;
    int kt = r >> 1, h = r & 1;
    int tid = threadIdx.x;
    __hip_bfloat16* dst = wt + (size_t)blk * HALF;
#pragma unroll
    for (int it = 0; it < 4; ++it) {
        int e = (it * 256 + tid) * 8;
        int g = e >> 9;
        int l = (e >> 3) & 63;
        int o  = nb * BN + h * 128 + (g >> 1) * 16 + (l & 15);
        int k0 = kt * BK + (g & 1) * 32 + (l >> 4) * 8;
        const fvec4* sw = (const fvec4*)(W + (size_t)o * KF + k0);
        const fvec4* sa = (const fvec4*)(A + (size_t)(o & 1023) * 1024 + (k0 & 1023));
        fvec4 w0 = sw[0], w1 = sw[1];
        fvec4 a0 = sa[0], a1 = sa[1];
        union { bf16x8 v; __hip_bfloat16 hh[8]; } ov;
        ov.hh[0] = __float2bfloat16(w0[0] + a0[0]); ov.hh[1] = __float2bfloat16(w0[1] + a0[1]);
        ov.hh[2] = __float2bfloat16(w0[2] + a0[2]); ov.hh[3] = __float2bfloat16(w0[3] + a0[3]);
        ov.hh[4] = __float2bfloat16(w1[0] + a1[0]); ov.hh[5] = __float2bfloat16(w1[1] + a1[1]);
        ov.hh[6] = __float2bfloat16(w1[2] + a1[2]); ov.hh[7] = __float2bfloat16(w1[3] + a1[3]);
        *(bf16x8*)(dst + e) = ov.v;
    }
}

// ---------------- async global->LDS (width 16) ----------------
__device__ inline void gload_lds16(const __hip_bfloat16* g, __hip_bfloat16* l) {
    __builtin_amdgcn_global_load_lds(
        (const __attribute__((address_space(1))) unsigned int*)g,
        (__attribute__((address_space(3))) unsigned int*)l, 16, 0, 0);
}

// stage one half-tile (2 gloads per thread = 16 KB)
#define STG_A(u, h, d) { const __hip_bfloat16* g_ = aP + (size_t)((u) * 2 + (h)) * HALF + t8; \
    __hip_bfloat16* l_ = As + ((d) * 2 + (h)) * HALF + t8;                        \
    gload_lds16(g_, l_); gload_lds16(g_ + 4096, l_ + 4096); }
#define STG_B(u, h, d) { const __hip_bfloat16* g_ = bP + (size_t)((u) * 2 + (h)) * HALF + t8; \
    __hip_bfloat16* l_ = Bs + ((d) * 2 + (h)) * HALF + t8;                        \
    gload_lds16(g_, l_); gload_lds16(g_ + 4096, l_ + 4096); }

// ds_read subtiles (fragment-major: base + lane*16B, conflict-free)
#define RD_A(d, mq) { const __hip_bfloat16* p_ = As + ((d) * 2 + wm) * HALF + (mq) * 4096 + lane8; \
    Af[0] = *(const bf16x8*)(p_);        Af[1] = *(const bf16x8*)(p_ + 512);      \
    Af[2] = *(const bf16x8*)(p_ + 1024); Af[3] = *(const bf16x8*)(p_ + 1536);     \
    Af[4] = *(const bf16x8*)(p_ + 2048); Af[5] = *(const bf16x8*)(p_ + 2560);     \
    Af[6] = *(const bf16x8*)(p_ + 3072); Af[7] = *(const bf16x8*)(p_ + 3584); }
#define RD_B(dst, d, nq) { const __hip_bfloat16* p_ = Bs + ((d) * 2 + bh) * HALF + bn + (nq) * 2048 + lane8; \
    dst[0] = *(const bf16x8*)(p_);        dst[1] = *(const bf16x8*)(p_ + 512);    \
    dst[2] = *(const bf16x8*)(p_ + 1024); dst[3] = *(const bf16x8*)(p_ + 1536); }

#define BAR_IN {                                                                  \
    asm volatile("" ::: "memory");                                                \
    __builtin_amdgcn_s_barrier();                                                 \
    __builtin_amdgcn_sched_barrier(0); }

#define BAR_OUT {                                                                 \
    asm volatile("" ::: "memory");                                                \
    __builtin_amdgcn_s_barrier();                                                 \
    asm volatile("" ::: "memory"); }

#define BAR_OUT_V4 {                                                              \
    asm volatile("s_waitcnt vmcnt(4)" ::: "memory");                              \
    __builtin_amdgcn_s_barrier();                                                 \
    asm volatile("" ::: "memory"); }

// 16 MFMA for quadrant (mq, nq): acc[mq*4+m][nq*2+n] += A(m,kk) x B(n,kk)
#define MM(mq, nq, BF) {                                                          \
    __builtin_amdgcn_s_setprio(1);                                                \
    _Pragma("unroll") for (int m = 0; m < 4; ++m)                                 \
        _Pragma("unroll") for (int n = 0; n < 2; ++n) {                           \
            acc[(mq) * 4 + m][(nq) * 2 + n] = __builtin_amdgcn_mfma_f32_16x16x32_bf16( \
                Af[m * 2 + 0], BF[n * 2 + 0], acc[(mq) * 4 + m][(nq) * 2 + n], 0, 0, 0); \
            acc[(mq) * 4 + m][(nq) * 2 + n] = __builtin_amdgcn_mfma_f32_16x16x32_bf16( \
                Af[m * 2 + 1], BF[n * 2 + 1], acc[(mq) * 4 + m][(nq) * 2 + n], 0, 0, 0); \
        }                                                                         \
    __builtin_amdgcn_s_setprio(0); }

// one K64-tile = 4 phases; stages: p1 A(u+1,0), p2 A(u+1,1), p3 B(u+2,0),
// p4 B(u+2,1); vmcnt(4) only at p4 (drains everything but B(u+2,*)).
#define TILE64(u, d) {                                                            \
    RD_A(d, 0) RD_B(Bf0, d, 0)                                                    \
    STG_A(((u) + 1) & 63, 0, (d) ^ 1)                                             \
    BAR_IN  MM(0, 0, Bf0) BAR_OUT                                                 \
    RD_B(Bf1, d, 1)                                                               \
    STG_A(((u) + 1) & 63, 1, (d) ^ 1)                                             \
    BAR_IN  MM(0, 1, Bf1) BAR_OUT                                                 \
    RD_A(d, 1)                                                                    \
    STG_B(((u) + 2) & 63, 0, d)                                                   \
    BAR_IN  MM(1, 0, Bf0) BAR_OUT                                                 \
    STG_B(((u) + 2) & 63, 1, d)                                                   \
    BAR_IN  MM(1, 1, Bf1) BAR_OUT_V4 }

__global__ __launch_bounds__(512, 2) void gemm_bf16_kernel(
    const __hip_bfloat16* __restrict__ xt, const __hip_bfloat16* __restrict__ wt,
    const float* __restrict__ bias, float* __restrict__ out) {
    extern __shared__ __hip_bfloat16 lds[];
    __hip_bfloat16* As = lds;                 // 2buf x 2half x 8192 = 32768
    __hip_bfloat16* Bs = lds + 32768;         // same

    // XCD chunking, nb-major inside chunk (B-panels L2-resident per XCD)
    int bid = blockIdx.x;                     // nwg = 1024
    int wg = (bid & 7) * 128 + (bid >> 3);
    int nb = wg >> 6;                         // 16 col-blocks
    int mb = wg & 63;                         // 64 row-blocks

    int tid = threadIdx.x;
    int lane = tid & 63;
    int wv = tid >> 6;                        // 8 waves
    int wm = wv >> 2, wn = wv & 3;            // 2M x 4N, 128x64 C each
    int bh = wn >> 1;                         // B half this wave reads
    int bn = (wn & 1) * 4096;                 // col-block offset within half
    int lane8 = lane * 8;
    int t8 = tid * 8;

    const __hip_bfloat16* aP = xt + (size_t)mb * (KT * 2 * HALF);
    const __hip_bfloat16* bP = wt + (size_t)nb * (KT * 2 * HALF);

    f32x4 acc[8][4];
#pragma unroll
    for (int mf = 0; mf < 8; ++mf)
#pragma unroll
        for (int nf = 0; nf < 4; ++nf) acc[mf][nf] = f32x4{0.f, 0.f, 0.f, 0.f};
    bf16x8 Af[8], Bf0[4], Bf1[4];

    // prologue: tile 0 (4 halves) + B(1,*); vmcnt(4) drains tile 0
    STG_A(0, 0, 0) STG_A(0, 1, 0) STG_B(0, 0, 0) STG_B(0, 1, 0)
    STG_B(1, 0, 1) STG_B(1, 1, 1)
    asm volatile("s_waitcnt vmcnt(4)" ::: "memory");
    __builtin_amdgcn_s_barrier();
    asm volatile("" ::: "memory");

    for (int uu = 0; uu < KT; uu += 2) {
        TILE64(uu, 0)
        TILE64(uu + 1, 1)
    }
    // drain all LDS-DMA before kernel end
    asm volatile("s_waitcnt vmcnt(0)" ::: "memory");

    // epilogue: C/D col = lane&15, row = (lane>>4)*4 + jj
    int row0 = mb * BM + wm * 128;
    int col0 = nb * BN + wn * 64;
    int lr = lane & 15;
    int hi = lane >> 4;
#pragma unroll
    for (int nf = 0; nf < 4; ++nf) {
        int col = col0 + nf * 16 + lr;
        float bv = bias[col];
#pragma unroll
        for (int mf = 0; mf < 8; ++mf) {
            int row = row0 + mf * 16 + hi * 4;
#pragma unroll
            for (int jj = 0; jj < 4; ++jj)
                out[(size_t)(row + jj) * NF + col] = acc[mf][nf][jj] + bv;
        }
    }
}

extern "C" void kernel_launch(void* const* d_in, const int* in_sizes, int n_in,
                              void* d_out, int out_size, void* d_ws, size_t ws_size,
                              hipStream_t stream) {
    const float* x = (const float*)d_in[0];
    const float* W = (const float*)d_in[1];
    const float* b = (const float*)d_in[2];
    const float* A = (const float*)d_in[3];
    float* out = (float*)d_out;

    size_t xt_elems = (size_t)MB * KT * 2 * HALF;   // 67.1M elems
    size_t wt_elems = (size_t)NB * KT * 2 * HALF;   // 16.8M elems
    size_t need = (xt_elems + wt_elems) * sizeof(__hip_bfloat16);
    if (ws_size < need) return;

    __hip_bfloat16* xt = (__hip_bfloat16*)d_ws;
    __hip_bfloat16* wt = xt + xt_elems;

    (void)hipFuncSetAttribute((const void*)gemm_bf16_kernel,
                              hipFuncAttributeMaxDynamicSharedMemorySize, 131072);

    tile_x_kernel<<<MB * KT * 2, 256, 0, stream>>>(x, xt);
    tile_w_kernel<<<NB * KT * 2, 256, 0, stream>>>(W, A, wt);
    gemm_bf16_kernel<<<MB * NB, 512, 131072, stream>>>(xt, wt, b, out);
}